// Round 8
// baseline (543.804 us; speedup 1.0000x reference)
//
#include <hip/hip_runtime.h>
#include <hip/hip_bf16.h>

typedef __bf16 bf16;
typedef __bf16 bf16x8 __attribute__((ext_vector_type(8)));
typedef float f32x4 __attribute__((ext_vector_type(4)));

#define LDST 264   // slab row stride in bf16 elems: 528 B (16B-aligned, 4-bank shift/row)

// ---------------- prep: transpose big weights -> bf16, PERMUTED slots, K-OUTER packed ----------------
// Logical col c -> slot ns = (c&~31) | (c odd ? 16+(c&31)/2 : (c&31)/2)   (permute within 32-groups)
// Storage: wpk[k>>3][slot][k&7]  (elem = (k>>3)*2048 + slot*8 + (k&7))
// -> per (kk,quad) the 16 B-frags of a wave are one contiguous 4KB region (imm-offset addressing,
//    coalesced 256B runs, all waves hit the same region -> L1/L2 reuse).
__global__ void transpose_all(const float* __restrict__ w0, const float* __restrict__ w1,
                              const float* __restrict__ w2, const float* __restrict__ w3,
                              bf16* __restrict__ out)
{
    __shared__ float tile[64][65];
    const int mz  = blockIdx.z;             // 0..23 = mat*6 + level
    const int mat = mz / 6;
    const float* srcs[4] = {w0, w1, w2, w3};
    const float* src = srcs[mat] + (size_t)(mz % 6) * 65536;
    bf16* dst = out + (size_t)mz * 65536;
    const int k0 = blockIdx.x * 64;
    const int n0 = blockIdx.y * 64;
    const int tx = threadIdx.x & 63, ty = threadIdx.x >> 6;
#pragma unroll
    for (int i = ty; i < 64; i += 4)
        tile[i][tx] = src[(size_t)(k0 + i) * 256 + n0 + tx];
    __syncthreads();
#pragma unroll
    for (int i = ty; i < 64; i += 4) {
        int n  = n0 + i;
        int o  = n & 31;
        int ns = (n & ~31) | ((o & 1) ? 16 + (o >> 1) : (o >> 1));
        int k  = k0 + tx;
        dst[(size_t)(k >> 3) * 2048 + ns * 8 + (k & 7)] = (bf16)tile[tx][i];
    }
}

// ---------------- prep: [6][256][10] -> [6][16][256] bf16, transposed + zero-padded (both w3s) ----------------
__global__ void prep_small(const float* __restrict__ cw3, const float* __restrict__ rw3,
                           bf16* __restrict__ outc, bf16* __restrict__ outr)
{
    int idx = blockIdx.x * 256 + threadIdx.x;  // 0..49151
    const float* w = (idx < 24576) ? cw3 : rw3;
    bf16* o = (idx < 24576) ? outc : outr;
    int j = (idx < 24576) ? idx : idx - 24576;
    int k = j & 255;
    int n = (j >> 8) & 15;
    int l = j >> 12;
    float v = (n < 10) ? w[((size_t)l * 256 + k) * 10 + n] : 0.0f;
    o[j] = (bf16)v;
}

// ---------------- helpers ----------------
__device__ __forceinline__ unsigned int pack2(float lo, float hi)
{
    union { bf16 h[2]; unsigned int u; } p;
    p.h[0] = (bf16)lo; p.h[1] = (bf16)hi;
    return p.u;
}

// VALU-pipe lane-reduce step: x += x[dpp-permuted lane]
template<int CTRL>
__device__ __forceinline__ float dppadd(float x)
{
    int y = __builtin_amdgcn_update_dpp(0, __float_as_int(x), CTRL, 0xF, 0xF, true);
    return x + __int_as_float(y);
}
// full sum across the 16-lane DPP row (= one quad); result broadcast to all 16 lanes
__device__ __forceinline__ float dppsum16(float x)
{
    x = dppadd<0xB1>(x);   // quad_perm [1,0,3,2]
    x = dppadd<0x4E>(x);   // quad_perm [2,3,0,1]
    x = dppadd<0x141>(x);  // row_half_mirror
    x = dppadd<0x140>(x);  // row_mirror
    return x;
}

// stage 16 rows of h (fp32 global) -> bf16 slab; wave-private, no barrier
__device__ __forceinline__ void stage_h16(bf16* slab, const float* __restrict__ hs,
                                          int l, int row0w, int lane)
{
#pragma unroll 4
    for (int ri = 0; ri < 16; ri++) {
        const int r = row0w + ri;
        const int b = r / 900;
        const int q = r - b * 900;
        const float4* src = (const float4*)(hs + (((size_t)l * 900 + q) * 32 + b) * 256);
        float4 vv = src[lane];
        union { bf16 h[4]; uint2 u; } pk;
        pk.h[0] = (bf16)vv.x; pk.h[1] = (bf16)vv.y; pk.h[2] = (bf16)vv.z; pk.h[3] = (bf16)vv.w;
        *(uint2*)&slab[ri * LDST + lane * 4] = pk.u;
    }
}

// 16x256 full-row GEMM, software-pipelined: B in two 8-frag chunks, next chunk's loads issued
// BEFORE current chunk's MFMAs; A (LDS) double-buffered one kk ahead. acc[nt] covers slot rows
// [16nt,16nt+16) = even (nt=2sg) / odd (nt=2sg+1) logical cols of 32-group sg.
__device__ __forceinline__ void gemmFR16(const bf16* slab, const bf16* __restrict__ wt,
                                         int lane, f32x4 acc[16])
{
    const int quad = lane >> 4, lx = lane & 15;
#pragma unroll
    for (int nt = 0; nt < 16; nt++) acc[nt] = f32x4{0.f, 0.f, 0.f, 0.f};
    const bf16* base = wt + (size_t)quad * 2048 + lx * 8;
    bf16x8 b0[8], b1[8];
    bf16x8 a = *(const bf16x8*)&slab[lx * LDST + quad * 8];          // A(kk=0)
#pragma unroll
    for (int j = 0; j < 8; j++)                                      // chunk0(kk=0)
        b0[j] = *(const bf16x8*)(base + j * 128);
#pragma unroll
    for (int kk = 0; kk < 8; kk++) {
        const bf16* bp = base + kk * 8192;
#pragma unroll
        for (int j = 0; j < 8; j++)                                  // chunk1(kk) loads lead...
            b1[j] = *(const bf16x8*)(bp + (8 + j) * 128);
#pragma unroll
        for (int j = 0; j < 8; j++)                                  // ...chunk0(kk) MFMAs
            acc[j] = __builtin_amdgcn_mfma_f32_16x16x32_bf16(a, b0[j], acc[j], 0, 0, 0);
        bf16x8 an = a;
        if (kk < 7) {
            an = *(const bf16x8*)&slab[lx * LDST + (kk + 1) * 32 + quad * 8];
#pragma unroll
            for (int j = 0; j < 8; j++)                              // chunk0(kk+1) loads lead...
                b0[j] = *(const bf16x8*)(bp + 8192 + j * 128);
        }
#pragma unroll
        for (int j = 0; j < 8; j++)                                  // ...chunk1(kk) MFMAs
            acc[8 + j] = __builtin_amdgcn_mfma_f32_16x16x32_bf16(a, b1[j], acc[8 + j], 0, 0, 0);
        a = an;
    }
}

// 16x256 @ 256x16 (small layers; weights [slot][256], unpermuted); A = slab rows 0..15
__device__ __forceinline__ f32x4 gemm16(const bf16* slab, const bf16* __restrict__ wt, int lane)
{
    const int quad = lane >> 4, lx = lane & 15;
    f32x4 acc = f32x4{0.f, 0.f, 0.f, 0.f};
#pragma unroll
    for (int kk = 0; kk < 8; kk++) {
        const int k0 = kk * 32 + quad * 8;
        bf16x8 a = *(const bf16x8*)&slab[lx * LDST + k0];
        bf16x8 b = *(const bf16x8*)&wt[lx * 256 + k0];
        acc = __builtin_amdgcn_mfma_f32_16x16x32_bf16(a, b, acc, 0, 0, 0);
    }
    return acc;
}

// wave-local LN: bias add, stats via in-reg nt-sum + dppsum16 (stats land in the owning lanes), norm+relu
__device__ __forceinline__ void ln_epi(f32x4 acc[16], const float* __restrict__ bias,
                                       const float* __restrict__ g, const float* __restrict__ bb,
                                       int lane)
{
    const int lx = lane & 15;
    float s[4] = {0.f, 0.f, 0.f, 0.f}, ss[4] = {0.f, 0.f, 0.f, 0.f};
#pragma unroll
    for (int sg = 0; sg < 8; sg++) {
        const float2 bv = *(const float2*)&bias[sg * 32 + 2 * lx];
#pragma unroll
        for (int r = 0; r < 4; r++) {
            float a0 = acc[2 * sg][r] + bv.x;
            float a1 = acc[2 * sg + 1][r] + bv.y;
            acc[2 * sg][r] = a0; acc[2 * sg + 1][r] = a1;
            s[r]  += a0 + a1;
            ss[r] += a0 * a0 + a1 * a1;
        }
    }
    float mean[4], rstd[4];
#pragma unroll
    for (int r = 0; r < 4; r++) {
        float st  = dppsum16(s[r]);
        float sst = dppsum16(ss[r]);
        mean[r] = st * (1.f / 256.f);
        float var = sst * (1.f / 256.f) - mean[r] * mean[r];
        rstd[r] = rsqrtf(var + 1e-5f);
    }
#pragma unroll
    for (int sg = 0; sg < 8; sg++) {
        const float2 gv  = *(const float2*)&g[sg * 32 + 2 * lx];
        const float2 bv2 = *(const float2*)&bb[sg * 32 + 2 * lx];
#pragma unroll
        for (int r = 0; r < 4; r++) {
            acc[2 * sg][r]     = fmaxf((acc[2 * sg][r]     - mean[r]) * rstd[r] * gv.x + bv2.x, 0.f);
            acc[2 * sg + 1][r] = fmaxf((acc[2 * sg + 1][r] - mean[r]) * rstd[r] * gv.y + bv2.y, 0.f);
        }
    }
}

__device__ __forceinline__ void bias_epi(f32x4 acc[16], const float* __restrict__ bias, int lane)
{
    const int lx = lane & 15;
#pragma unroll
    for (int sg = 0; sg < 8; sg++) {
        const float2 bv = *(const float2*)&bias[sg * 32 + 2 * lx];
#pragma unroll
        for (int r = 0; r < 4; r++) {
            acc[2 * sg][r]     = fmaxf(acc[2 * sg][r]     + bv.x, 0.f);
            acc[2 * sg + 1][r] = fmaxf(acc[2 * sg + 1][r] + bv.y, 0.f);
        }
    }
}

// shuffle-free slab store: lane lx owns logical cols (32sg+2lx, 32sg+2lx+1); wave-order makes
// in-place reuse safe (same-wave DS ops retire in order), no barrier.
__device__ __forceinline__ void store_slab(bf16* slab, int lane, const f32x4 acc[16])
{
    const int quad = lane >> 4, lx = lane & 15;
#pragma unroll
    for (int sg = 0; sg < 8; sg++)
#pragma unroll
        for (int r = 0; r < 4; r++)
            *(unsigned int*)&slab[(quad * 4 + r) * LDST + sg * 32 + 2 * lx] =
                pack2(acc[2 * sg][r], acc[2 * sg + 1][r]);
}

// ---------------- main fused head kernel ----------------
// CHAIN-SPLIT: blockIdx.z = 0 -> cls chain, 1 -> reg chain. Each block runs only 3 dependent
// GEMMs (halved serial chain, halved executed code, 2x wave supply). ZERO block barriers;
// one 16-row slice per wave; wave-local LN; M=16 register budget (R4-proven, no spill).
__global__ __launch_bounds__(256, 2) void head_kernel(
    const float* __restrict__ hs, const float* __restrict__ init_ref,
    const float* __restrict__ inter_ref,
    const bf16* __restrict__ cw1t, const bf16* __restrict__ cw2t,
    const bf16* __restrict__ rw1t, const bf16* __restrict__ rw2t,
    const bf16* __restrict__ cw3t, const bf16* __restrict__ rw3t,
    const float* __restrict__ cb1, const float* __restrict__ g1, const float* __restrict__ b1,
    const float* __restrict__ cb2, const float* __restrict__ g2, const float* __restrict__ b2,
    const float* __restrict__ cb3,
    const float* __restrict__ rb1, const float* __restrict__ rb2, const float* __restrict__ rb3,
    float* __restrict__ out)
{
    __shared__ __align__(16) bf16 slabs[4][16 * LDST];   // 8.4 KB per wave, private; 33.8 KB/block

    const int l     = blockIdx.y;
    const int chain = blockIdx.z;                        // 0 = cls, 1 = reg
    const int tid   = threadIdx.x;
    const int wave  = tid >> 6;
    const int lane  = tid & 63;
    const int quad  = lane >> 4;
    const int lx    = lane & 15;
    const int row0w = blockIdx.x * 64 + wave * 16;       // wave's first logical row (within level l)
    bf16* slab = slabs[wave];

    const bf16* w1 = (chain ? rw1t : cw1t) + (size_t)l * 65536;
    const bf16* w2 = (chain ? rw2t : cw2t) + (size_t)l * 65536;
    const bf16* w3 = (chain ? rw3t : cw3t) + (size_t)l * 4096;

    f32x4 acc[16];

    // ===== stage h, layer1 -> slab (in place over h) =====
    stage_h16(slab, hs, l, row0w, lane);
    gemmFR16(slab, w1, lane, acc);
    if (chain == 0) ln_epi(acc, cb1 + l * 256, g1 + l * 256, b1 + l * 256, lane);
    else            bias_epi(acc, rb1 + l * 256, lane);
    store_slab(slab, lane, acc);

    // ===== layer2 -> slab =====
    gemmFR16(slab, w2, lane, acc);
    if (chain == 0) ln_epi(acc, cb2 + l * 256, g2 + l * 256, b2 + l * 256, lane);
    else            bias_epi(acc, rb2 + l * 256, lane);
    store_slab(slab, lane, acc);

    // ===== layer3: 16-col head + output =====
    f32x4 t = gemm16(slab, w3, lane);
    if (chain == 0) {
        if (lx < 10) {
            const float bv = cb3[l * 10 + lx];
#pragma unroll
            for (int r = 0; r < 4; r++) {
                int row = row0w + quad * 4 + r;
                out[((size_t)l * 28800 + row) * 10 + lx] = t[r] + bv;
            }
        }
    } else {
        if (lx < 10) {
            const float bv = rb3[l * 10 + lx];
            const float* refp = (l == 0) ? init_ref : (inter_ref + (size_t)(l - 1) * 28800 * 3);
#pragma unroll
            for (int r = 0; r < 4; r++) {
                int row = row0w + quad * 4 + r;
                float vv = t[r] + bv;
                float o;
                if (lx == 0 || lx == 1 || lx == 4) {
                    int rc = (lx == 4) ? 2 : lx;
                    float x = refp[(size_t)row * 3 + rc];
                    x = fminf(fmaxf(x, 0.f), 1.f);
                    float x1 = fmaxf(x, 1e-5f);
                    float x2 = fmaxf(1.f - x, 1e-5f);
                    float ris = logf(x1) - logf(x2);
                    float sg = 1.f / (1.f + expf(-(vv + ris)));
                    o = (lx == 4) ? (sg * 8.f - 5.f) : (sg * 102.4f - 51.2f);
                } else {
                    o = vv;
                }
                out[(size_t)(6 + l) * 28800 * 10 + (size_t)row * 10 + lx] = o;
            }
        }
    }
}

extern "C" void kernel_launch(void* const* d_in, const int* in_sizes, int n_in,
                              void* d_out, int out_size, void* d_ws, size_t ws_size,
                              hipStream_t stream)
{
    const float* hs        = (const float*)d_in[0];
    const float* init_ref  = (const float*)d_in[1];
    const float* inter_ref = (const float*)d_in[2];
    const float* cls_w1    = (const float*)d_in[3];
    const float* cls_b1    = (const float*)d_in[4];
    const float* ln1_g     = (const float*)d_in[5];
    const float* ln1_b     = (const float*)d_in[6];
    const float* cls_w2    = (const float*)d_in[7];
    const float* cls_b2    = (const float*)d_in[8];
    const float* ln2_g     = (const float*)d_in[9];
    const float* ln2_b     = (const float*)d_in[10];
    const float* cls_w3    = (const float*)d_in[11];
    const float* cls_b3    = (const float*)d_in[12];
    const float* reg_w1    = (const float*)d_in[13];
    const float* reg_b1    = (const float*)d_in[14];
    const float* reg_w2    = (const float*)d_in[15];
    const float* reg_b2    = (const float*)d_in[16];
    const float* reg_w3    = (const float*)d_in[17];
    const float* reg_b3    = (const float*)d_in[18];

    bf16* ws   = (bf16*)d_ws;
    bf16* cw1t = ws;                  // 4 contiguous 6*65536 regions (K-outer packed)
    bf16* cw2t = cw1t + 393216;
    bf16* rw1t = cw2t + 393216;
    bf16* rw2t = rw1t + 393216;
    bf16* cw3t = rw2t + 393216;       // 6*16*256
    bf16* rw3t = cw3t + 24576;

    transpose_all<<<dim3(4, 4, 24), 256, 0, stream>>>(cls_w1, cls_w2, reg_w1, reg_w2, cw1t);
    prep_small<<<192, 256, 0, stream>>>(cls_w3, reg_w3, cw3t, rw3t);

    head_kernel<<<dim3(450, 6, 2), 256, 0, stream>>>(
        hs, init_ref, inter_ref,
        cw1t, cw2t, rw1t, rw2t, cw3t, rw3t,
        cls_b1, ln1_g, ln1_b, cls_b2, ln2_g, ln2_b, cls_b3,
        reg_b1, reg_b2, reg_b3, (float*)d_out);
}

// Round 9
// 460.371 us; speedup vs baseline: 1.1812x; 1.1812x over previous
//
#include <hip/hip_runtime.h>
#include <hip/hip_bf16.h>

typedef __bf16 bf16;
typedef __bf16 bf16x8 __attribute__((ext_vector_type(8)));
typedef float f32x4 __attribute__((ext_vector_type(4)));

// A-buffer: K-outer packed, 64 rows. elem(k,row) = (k>>3)*528 + row*8 + (k&7)
// (group = 64 rows x 8 k = 512 elems + 16 pad -> store bank spread). 32 groups x 528 x 2B = 33792 B.
#define AG 528

// ---------------- prep: transpose big weights -> bf16, PERMUTED slots, K-OUTER packed ----------------
// Logical col c -> slot ns = (c&~31) | (c odd ? 16+(c&31)/2 : (c&31)/2)   (permute within 32-groups)
// Storage: wpk[k>>3][slot][k&7]  (elem = (k>>3)*2048 + slot*8 + (k&7))
// -> per (kk,quad) a wave's B-frags are contiguous 16B runs at imm offsets; waves reading the same
//    slice back-to-back hit L1.
__global__ void transpose_all(const float* __restrict__ w0, const float* __restrict__ w1,
                              const float* __restrict__ w2, const float* __restrict__ w3,
                              bf16* __restrict__ out)
{
    __shared__ float tile[64][65];
    const int mz  = blockIdx.z;             // 0..23 = mat*6 + level
    const int mat = mz / 6;
    const float* srcs[4] = {w0, w1, w2, w3};
    const float* src = srcs[mat] + (size_t)(mz % 6) * 65536;
    bf16* dst = out + (size_t)mz * 65536;
    const int k0 = blockIdx.x * 64;
    const int n0 = blockIdx.y * 64;
    const int tx = threadIdx.x & 63, ty = threadIdx.x >> 6;
#pragma unroll
    for (int i = ty; i < 64; i += 4)
        tile[i][tx] = src[(size_t)(k0 + i) * 256 + n0 + tx];
    __syncthreads();
#pragma unroll
    for (int i = ty; i < 64; i += 4) {
        int n  = n0 + i;
        int o  = n & 31;
        int ns = (n & ~31) | ((o & 1) ? 16 + (o >> 1) : (o >> 1));
        int k  = k0 + tx;
        dst[(size_t)(k >> 3) * 2048 + ns * 8 + (k & 7)] = (bf16)tile[tx][i];
    }
}

// ---------------- prep: [6][256][10] -> [6][16][256] bf16, transposed + zero-padded (both w3s) ----------------
__global__ void prep_small(const float* __restrict__ cw3, const float* __restrict__ rw3,
                           bf16* __restrict__ outc, bf16* __restrict__ outr)
{
    int idx = blockIdx.x * 256 + threadIdx.x;  // 0..49151
    const float* w = (idx < 24576) ? cw3 : rw3;
    bf16* o = (idx < 24576) ? outc : outr;
    int j = (idx < 24576) ? idx : idx - 24576;
    int k = j & 255;
    int n = (j >> 8) & 15;
    int l = j >> 12;
    float v = (n < 10) ? w[((size_t)l * 256 + k) * 10 + n] : 0.0f;
    o[j] = (bf16)v;
}

// ---------------- helpers ----------------
__device__ __forceinline__ unsigned int pack2(float lo, float hi)
{
    union { bf16 h[2]; unsigned int u; } p;
    p.h[0] = (bf16)lo; p.h[1] = (bf16)hi;
    return p.u;
}

template<int CTRL>
__device__ __forceinline__ float dppadd(float x)
{
    int y = __builtin_amdgcn_update_dpp(0, __float_as_int(x), CTRL, 0xF, 0xF, true);
    return x + __int_as_float(y);
}
// full sum across the 16-lane DPP row (= one quad); result broadcast to all 16 lanes
__device__ __forceinline__ float dppsum16(float x)
{
    x = dppadd<0xB1>(x);   // quad_perm [1,0,3,2]
    x = dppadd<0x4E>(x);   // quad_perm [2,3,0,1]
    x = dppadd<0x141>(x);  // row_half_mirror
    x = dppadd<0x140>(x);  // row_mirror
    return x;
}

// 32x128 wave-tile GEMM: rows [mw*32, +32), cols (slots) [nw*128, +128). acc[2 m][8 nt] = 64 regs.
// B software-pipelined one kk ahead; A from shared K-outer LDS buffer.
__device__ __forceinline__ void gemm32(const bf16* Ab, const bf16* __restrict__ wt,
                                       int mw, int nw, int lane, f32x4 acc[2][8])
{
    const int quad = lane >> 4, lx = lane & 15;
#pragma unroll
    for (int m = 0; m < 2; m++)
#pragma unroll
        for (int nt = 0; nt < 8; nt++)
            acc[m][nt] = f32x4{0.f, 0.f, 0.f, 0.f};
    const bf16* base = wt + (size_t)quad * 2048 + (nw * 128 + lx) * 8;
    const int ar = mw * 32 + lx;                    // A row for m=0 (m=1: +16)
    bf16x8 b0[8], b1[8];
#pragma unroll
    for (int nt = 0; nt < 8; nt++)
        b0[nt] = *(const bf16x8*)(base + nt * 128);
    bf16x8 a0 = *(const bf16x8*)&Ab[quad * AG + ar * 8];
    bf16x8 a1 = *(const bf16x8*)&Ab[quad * AG + (ar + 16) * 8];
#pragma unroll
    for (int kk = 0; kk < 8; kk++) {
        bf16x8* bc = (kk & 1) ? b1 : b0;
        bf16x8* bn = (kk & 1) ? b0 : b1;
        bf16x8 a0n = a0, a1n = a1;
        if (kk < 7) {
            const bf16* bp = base + (kk + 1) * 8192;
#pragma unroll
            for (int nt = 0; nt < 8; nt++)          // next-kk B loads lead...
                bn[nt] = *(const bf16x8*)(bp + nt * 128);
            a0n = *(const bf16x8*)&Ab[((kk + 1) * 4 + quad) * AG + ar * 8];
            a1n = *(const bf16x8*)&Ab[((kk + 1) * 4 + quad) * AG + (ar + 16) * 8];
        }
#pragma unroll
        for (int nt = 0; nt < 8; nt++) {            // ...current-kk MFMAs
            acc[0][nt] = __builtin_amdgcn_mfma_f32_16x16x32_bf16(a0, bc[nt], acc[0][nt], 0, 0, 0);
            acc[1][nt] = __builtin_amdgcn_mfma_f32_16x16x32_bf16(a1, bc[nt], acc[1][nt], 0, 0, 0);
        }
        a0 = a0n; a1 = a1n;
    }
}

// 16x256 @ 256x16 (small layers; weights [slot][256], unpermuted); A rows [mrow0, +16) from K-outer LDS
__device__ __forceinline__ f32x4 gemm16(const bf16* Ab, const bf16* __restrict__ wt,
                                        int mrow0, int lane)
{
    const int quad = lane >> 4, lx = lane & 15;
    f32x4 acc = f32x4{0.f, 0.f, 0.f, 0.f};
#pragma unroll
    for (int kk = 0; kk < 8; kk++) {
        bf16x8 a = *(const bf16x8*)&Ab[(kk * 4 + quad) * AG + (mrow0 + lx) * 8];
        bf16x8 b = *(const bf16x8*)&wt[lx * 256 + kk * 32 + quad * 8];
        acc = __builtin_amdgcn_mfma_f32_16x16x32_bf16(a, b, acc, 0, 0, 0);
    }
    return acc;
}

// bias add in place + per-row partial (sum,sumsq) over this wave's 128 cols via DPP -> redC[nw]
__device__ __forceinline__ void ln_partial(f32x4 acc[2][8], const float* __restrict__ bias,
                                           float2 (*redC)[64], int mw, int nw, int lane)
{
    const int quad = lane >> 4, lx = lane & 15;
    float s[2][4] = {}, ss[2][4] = {};
#pragma unroll
    for (int sg = 0; sg < 4; sg++) {
        const float2 bv = *(const float2*)&bias[nw * 128 + sg * 32 + 2 * lx];
#pragma unroll
        for (int m = 0; m < 2; m++)
#pragma unroll
            for (int r = 0; r < 4; r++) {
                float a0 = acc[m][2 * sg][r] + bv.x;
                float a1 = acc[m][2 * sg + 1][r] + bv.y;
                acc[m][2 * sg][r] = a0; acc[m][2 * sg + 1][r] = a1;
                s[m][r]  += a0 + a1;
                ss[m][r] += a0 * a0 + a1 * a1;
            }
    }
#pragma unroll
    for (int m = 0; m < 2; m++)
#pragma unroll
        for (int r = 0; r < 4; r++) {
            float sv  = dppsum16(s[m][r]);
            float ssv = dppsum16(ss[m][r]);
            if (lx == 0)
                redC[nw][mw * 32 + m * 16 + quad * 4 + r] = make_float2(sv, ssv);
        }
}

// normalize + relu in place; stat = redC[0][row] (mean, rstd)
__device__ __forceinline__ void ln_norm(f32x4 acc[2][8],
                                        const float* __restrict__ g, const float* __restrict__ bb,
                                        const float2 (*redC)[64], int mw, int nw, int lane)
{
    const int quad = lane >> 4, lx = lane & 15;
    float2 gv[4], bv[4];
#pragma unroll
    for (int sg = 0; sg < 4; sg++) {
        gv[sg] = *(const float2*)&g[nw * 128 + sg * 32 + 2 * lx];
        bv[sg] = *(const float2*)&bb[nw * 128 + sg * 32 + 2 * lx];
    }
#pragma unroll
    for (int m = 0; m < 2; m++)
#pragma unroll
        for (int r = 0; r < 4; r++) {
            float2 st = redC[0][mw * 32 + m * 16 + quad * 4 + r];
#pragma unroll
            for (int sg = 0; sg < 4; sg++) {
                acc[m][2 * sg][r]     = fmaxf((acc[m][2 * sg][r]     - st.x) * st.y * gv[sg].x + bv[sg].x, 0.f);
                acc[m][2 * sg + 1][r] = fmaxf((acc[m][2 * sg + 1][r] - st.x) * st.y * gv[sg].y + bv[sg].y, 0.f);
            }
        }
}

__device__ __forceinline__ void bias_relu(f32x4 acc[2][8], const float* __restrict__ bias,
                                          int nw, int lane)
{
    const int lx = lane & 15;
#pragma unroll
    for (int sg = 0; sg < 4; sg++) {
        const float2 bv = *(const float2*)&bias[nw * 128 + sg * 32 + 2 * lx];
#pragma unroll
        for (int m = 0; m < 2; m++)
#pragma unroll
            for (int r = 0; r < 4; r++) {
                acc[m][2 * sg][r]     = fmaxf(acc[m][2 * sg][r]     + bv.x, 0.f);
                acc[m][2 * sg + 1][r] = fmaxf(acc[m][2 * sg + 1][r] + bv.y, 0.f);
            }
    }
}

// shuffle-free store into K-outer A-buf: lane lx owns logical col pair (c, c+1),
// c = nw*128 + sg*32 + 2lx -> u32 at elem (c>>3)*AG + row*8 + (c&7)
__device__ __forceinline__ void store_A(bf16* Ab, int mw, int nw, int lane, const f32x4 acc[2][8])
{
    const int quad = lane >> 4, lx = lane & 15;
#pragma unroll
    for (int m = 0; m < 2; m++)
#pragma unroll
        for (int sg = 0; sg < 4; sg++) {
            const int cg = nw * 16 + sg * 4 + (lx >> 2);     // (c>>3)
            const int c7 = (2 * lx) & 7;                     // (c&7)
#pragma unroll
            for (int r = 0; r < 4; r++) {
                int row = mw * 32 + m * 16 + quad * 4 + r;
                *(unsigned int*)&Ab[cg * AG + row * 8 + c7] =
                    pack2(acc[m][2 * sg][r], acc[m][2 * sg + 1][r]);
            }
        }
}

// ---------------- main fused head kernel ----------------
// Block = 256 thr = 2x2 wave grid over 64 rows x 256 cols; wave = 32 rows x 128 cols (acc 64 regs).
// B-bytes/row cut 2-4x vs R8 (m-waves share B slices -> L1 hits). Chain-split (z: 0=cls, 1=reg).
// Barriers: cls 7, reg 5. LDS 34.8 KB -> 4 blocks/CU; (256,3) targets ~170-reg cap, 3 waves/SIMD.
__global__ __launch_bounds__(256, 3) void head_kernel(
    const float* __restrict__ hs, const float* __restrict__ init_ref,
    const float* __restrict__ inter_ref,
    const bf16* __restrict__ cw1t, const bf16* __restrict__ cw2t,
    const bf16* __restrict__ rw1t, const bf16* __restrict__ rw2t,
    const bf16* __restrict__ cw3t, const bf16* __restrict__ rw3t,
    const float* __restrict__ cb1, const float* __restrict__ g1, const float* __restrict__ b1,
    const float* __restrict__ cb2, const float* __restrict__ g2, const float* __restrict__ b2,
    const float* __restrict__ cb3,
    const float* __restrict__ rb1, const float* __restrict__ rb2, const float* __restrict__ rb3,
    float* __restrict__ out)
{
    __shared__ __align__(16) bf16 Ab[32 * AG];   // 33792 B
    __shared__ float2 redC[2][64];               // [nw][row]; redC[0] doubles as stat

    const int l     = blockIdx.y;
    const int chain = blockIdx.z;                // 0 = cls, 1 = reg
    const int tid   = threadIdx.x;
    const int wave  = tid >> 6;
    const int lane  = tid & 63;
    const int quad  = lane >> 4;
    const int lx    = lane & 15;
    const int mw    = wave >> 1;                 // rows [mw*32, +32)
    const int nw    = wave & 1;                  // cols [nw*128, +128)
    const int row0  = blockIdx.x * 64;

    // ---- stage h: wave stages rows [wave*16, +16) into K-outer A-buf ----
#pragma unroll 4
    for (int ri = 0; ri < 16; ri++) {
        const int r = row0 + wave * 16 + ri;
        const int b = r / 900;
        const int q = r - b * 900;
        const float4* src = (const float4*)(hs + (((size_t)l * 900 + q) * 32 + b) * 256);
        float4 vv = src[lane];
        union { bf16 h[4]; uint2 u; } pk;
        pk.h[0] = (bf16)vv.x; pk.h[1] = (bf16)vv.y; pk.h[2] = (bf16)vv.z; pk.h[3] = (bf16)vv.w;
        // k = lane*4: elem = (lane>>1)*AG + row*8 + (lane&1)*4
        *(uint2*)&Ab[(lane >> 1) * AG + (wave * 16 + ri) * 8 + (lane & 1) * 4] = pk.u;
    }
    __syncthreads();                                                    // S0: h staged

    const bf16* w1 = (chain ? rw1t : cw1t) + (size_t)l * 65536;
    const bf16* w2 = (chain ? rw2t : cw2t) + (size_t)l * 65536;
    const bf16* w3 = (chain ? rw3t : cw3t) + (size_t)l * 4096;

    f32x4 acc[2][8];

    // ===== layer 1 =====
    gemm32(Ab, w1, mw, nw, lane, acc);
    if (chain == 0) {
        ln_partial(acc, cb1 + l * 256, redC, mw, nw, lane);
        __syncthreads();                                                // B1: redC ready + A reads done
        if (tid < 64) {
            float2 x = redC[0][tid], y = redC[1][tid];
            float mean = (x.x + y.x) * (1.f / 256.f);
            float var  = (x.y + y.y) * (1.f / 256.f) - mean * mean;
            redC[0][tid] = make_float2(mean, rsqrtf(var + 1e-5f));
        }
        __syncthreads();                                                // B2: stat ready
        ln_norm(acc, g1 + l * 256, b1 + l * 256, redC, mw, nw, lane);
        store_A(Ab, mw, nw, lane, acc);
        __syncthreads();                                                // B3: x1 published
    } else {
        bias_relu(acc, rb1 + l * 256, nw, lane);
        __syncthreads();                                                // A reads done
        store_A(Ab, mw, nw, lane, acc);
        __syncthreads();                                                // y1 published
    }

    // ===== layer 2 =====
    gemm32(Ab, w2, mw, nw, lane, acc);
    if (chain == 0) {
        ln_partial(acc, cb2 + l * 256, redC, mw, nw, lane);
        __syncthreads();                                                // B4
        if (tid < 64) {
            float2 x = redC[0][tid], y = redC[1][tid];
            float mean = (x.x + y.x) * (1.f / 256.f);
            float var  = (x.y + y.y) * (1.f / 256.f) - mean * mean;
            redC[0][tid] = make_float2(mean, rsqrtf(var + 1e-5f));
        }
        __syncthreads();                                                // B5
        ln_norm(acc, g2 + l * 256, b2 + l * 256, redC, mw, nw, lane);
        store_A(Ab, mw, nw, lane, acc);
        __syncthreads();                                                // B6: x2 published
    } else {
        bias_relu(acc, rb2 + l * 256, nw, lane);
        __syncthreads();
        store_A(Ab, mw, nw, lane, acc);
        __syncthreads();                                                // y2 published
    }

    // ===== layer 3: wave handles rows [wave*16, +16) =====
    f32x4 t = gemm16(Ab, w3, wave * 16, lane);
    if (chain == 0) {
        if (lx < 10) {
            const float bv = cb3[l * 10 + lx];
#pragma unroll
            for (int r = 0; r < 4; r++) {
                int row = row0 + wave * 16 + quad * 4 + r;
                out[((size_t)l * 28800 + row) * 10 + lx] = t[r] + bv;
            }
        }
    } else {
        if (lx < 10) {
            const float bv = rb3[l * 10 + lx];
            const float* refp = (l == 0) ? init_ref : (inter_ref + (size_t)(l - 1) * 28800 * 3);
#pragma unroll
            for (int r = 0; r < 4; r++) {
                int row = row0 + wave * 16 + quad * 4 + r;
                float vv = t[r] + bv;
                float o;
                if (lx == 0 || lx == 1 || lx == 4) {
                    int rc = (lx == 4) ? 2 : lx;
                    float x = refp[(size_t)row * 3 + rc];
                    x = fminf(fmaxf(x, 0.f), 1.f);
                    float x1 = fmaxf(x, 1e-5f);
                    float x2 = fmaxf(1.f - x, 1e-5f);
                    float ris = logf(x1) - logf(x2);
                    float sg = 1.f / (1.f + expf(-(vv + ris)));
                    o = (lx == 4) ? (sg * 8.f - 5.f) : (sg * 102.4f - 51.2f);
                } else {
                    o = vv;
                }
                out[(size_t)(6 + l) * 28800 * 10 + (size_t)row * 10 + lx] = o;
            }
        }
    }
}

extern "C" void kernel_launch(void* const* d_in, const int* in_sizes, int n_in,
                              void* d_out, int out_size, void* d_ws, size_t ws_size,
                              hipStream_t stream)
{
    const float* hs        = (const float*)d_in[0];
    const float* init_ref  = (const float*)d_in[1];
    const float* inter_ref = (const float*)d_in[2];
    const float* cls_w1    = (const float*)d_in[3];
    const float* cls_b1    = (const float*)d_in[4];
    const float* ln1_g     = (const float*)d_in[5];
    const float* ln1_b     = (const float*)d_in[6];
    const float* cls_w2    = (const float*)d_in[7];
    const float* cls_b2    = (const float*)d_in[8];
    const float* ln2_g     = (const float*)d_in[9];
    const float* ln2_b     = (const float*)d_in[10];
    const float* cls_w3    = (const float*)d_in[11];
    const float* cls_b3    = (const float*)d_in[12];
    const float* reg_w1    = (const float*)d_in[13];
    const float* reg_b1    = (const float*)d_in[14];
    const float* reg_w2    = (const float*)d_in[15];
    const float* reg_b2    = (const float*)d_in[16];
    const float* reg_w3    = (const float*)d_in[17];
    const float* reg_b3    = (const float*)d_in[18];

    bf16* ws   = (bf16*)d_ws;
    bf16* cw1t = ws;                  // 4 contiguous 6*65536 regions (K-outer packed)
    bf16* cw2t = cw1t + 393216;
    bf16* rw1t = cw2t + 393216;
    bf16* rw2t = rw1t + 393216;
    bf16* cw3t = rw2t + 393216;       // 6*16*256
    bf16* rw3t = cw3t + 24576;

    transpose_all<<<dim3(4, 4, 24), 256, 0, stream>>>(cls_w1, cls_w2, reg_w1, reg_w2, cw1t);
    prep_small<<<192, 256, 0, stream>>>(cls_w3, reg_w3, cw3t, rw3t);

    head_kernel<<<dim3(450, 6, 2), 256, 0, stream>>>(
        hs, init_ref, inter_ref,
        cw1t, cw2t, rw1t, rw2t, cw3t, rw3t,
        cls_b1, ln1_g, ln1_b, cls_b2, ln2_g, ln2_b, cls_b3,
        reg_b1, reg_b2, reg_b3, (float*)d_out);
}

// Round 10
// 431.480 us; speedup vs baseline: 1.2603x; 1.0670x over previous
//
#include <hip/hip_runtime.h>
#include <hip/hip_bf16.h>

typedef __bf16 bf16;
typedef __bf16 bf16x8 __attribute__((ext_vector_type(8)));
typedef float f32x4 __attribute__((ext_vector_type(4)));

// A-buffer: K-outer packed, 64 rows. elem(k,row) = (k>>3)*528 + row*8 + (k&7)
// (group = 64 rows x 8 k = 512 elems + 16 pad -> store bank spread). 32 groups x 528 x 2B = 33792 B.
#define AG 528

// ---------------- prep: transpose big weights -> bf16, PERMUTED slots, K-OUTER packed ----------------
// Logical col c -> slot ns = (c&~31) | (c odd ? 16+(c&31)/2 : (c&31)/2)   (permute within 32-groups)
// Storage: wpk[k>>3][slot][k&7]  (elem = (k>>3)*2048 + slot*8 + (k&7))
__global__ void transpose_all(const float* __restrict__ w0, const float* __restrict__ w1,
                              const float* __restrict__ w2, const float* __restrict__ w3,
                              bf16* __restrict__ out)
{
    __shared__ float tile[64][65];
    const int mz  = blockIdx.z;             // 0..23 = mat*6 + level
    const int mat = mz / 6;
    const float* srcs[4] = {w0, w1, w2, w3};
    const float* src = srcs[mat] + (size_t)(mz % 6) * 65536;
    bf16* dst = out + (size_t)mz * 65536;
    const int k0 = blockIdx.x * 64;
    const int n0 = blockIdx.y * 64;
    const int tx = threadIdx.x & 63, ty = threadIdx.x >> 6;
#pragma unroll
    for (int i = ty; i < 64; i += 4)
        tile[i][tx] = src[(size_t)(k0 + i) * 256 + n0 + tx];
    __syncthreads();
#pragma unroll
    for (int i = ty; i < 64; i += 4) {
        int n  = n0 + i;
        int o  = n & 31;
        int ns = (n & ~31) | ((o & 1) ? 16 + (o >> 1) : (o >> 1));
        int k  = k0 + tx;
        dst[(size_t)(k >> 3) * 2048 + ns * 8 + (k & 7)] = (bf16)tile[tx][i];
    }
}

// ---------------- prep: [6][256][10] -> [6][16][256] bf16, transposed + zero-padded (both w3s) ----------------
__global__ void prep_small(const float* __restrict__ cw3, const float* __restrict__ rw3,
                           bf16* __restrict__ outc, bf16* __restrict__ outr)
{
    int idx = blockIdx.x * 256 + threadIdx.x;  // 0..49151
    const float* w = (idx < 24576) ? cw3 : rw3;
    bf16* o = (idx < 24576) ? outc : outr;
    int j = (idx < 24576) ? idx : idx - 24576;
    int k = j & 255;
    int n = (j >> 8) & 15;
    int l = j >> 12;
    float v = (n < 10) ? w[((size_t)l * 256 + k) * 10 + n] : 0.0f;
    o[j] = (bf16)v;
}

// ---------------- helpers ----------------
__device__ __forceinline__ unsigned int pack2(float lo, float hi)
{
    union { bf16 h[2]; unsigned int u; } p;
    p.h[0] = (bf16)lo; p.h[1] = (bf16)hi;
    return p.u;
}

template<int CTRL>
__device__ __forceinline__ float dppadd(float x)
{
    int y = __builtin_amdgcn_update_dpp(0, __float_as_int(x), CTRL, 0xF, 0xF, true);
    return x + __int_as_float(y);
}
// full sum across the 16-lane DPP row (= one quad); result broadcast to all 16 lanes
__device__ __forceinline__ float dppsum16(float x)
{
    x = dppadd<0xB1>(x);   // quad_perm [1,0,3,2]
    x = dppadd<0x4E>(x);   // quad_perm [2,3,0,1]
    x = dppadd<0x141>(x);  // row_half_mirror
    x = dppadd<0x140>(x);  // row_mirror
    return x;
}

// 64x64 wave-tile GEMM: ALL 64 rows x cols (slots) [nw*64, +64). acc[4 m][4 nt] = 64 regs.
// Each B-frag feeds FOUR MFMAs -> halves B port bytes vs R9's 32x128 tile.
// A and B double-buffered one kk ahead (parity arrays, statically indexed under full unroll).
__device__ __forceinline__ void gemm64(const bf16* Ab, const bf16* __restrict__ wt,
                                       int nw, int lane, f32x4 acc[4][4])
{
    const int quad = lane >> 4, lx = lane & 15;
#pragma unroll
    for (int m = 0; m < 4; m++)
#pragma unroll
        for (int nt = 0; nt < 4; nt++)
            acc[m][nt] = f32x4{0.f, 0.f, 0.f, 0.f};
    const bf16* base = wt + (size_t)quad * 2048 + (nw * 64 + lx) * 8;
    bf16x8 a0[4], a1[4], b0[4], b1[4];
#pragma unroll
    for (int nt = 0; nt < 4; nt++)
        b0[nt] = *(const bf16x8*)(base + nt * 128);
#pragma unroll
    for (int m = 0; m < 4; m++)
        a0[m] = *(const bf16x8*)&Ab[quad * AG + (m * 16 + lx) * 8];
#pragma unroll
    for (int kk = 0; kk < 8; kk++) {
        bf16x8* ac = (kk & 1) ? a1 : a0;
        bf16x8* an = (kk & 1) ? a0 : a1;
        bf16x8* bc = (kk & 1) ? b1 : b0;
        bf16x8* bn = (kk & 1) ? b0 : b1;
        if (kk < 7) {
            const bf16* bp = base + (kk + 1) * 8192;
#pragma unroll
            for (int nt = 0; nt < 4; nt++)          // next-kk B loads lead...
                bn[nt] = *(const bf16x8*)(bp + nt * 128);
#pragma unroll
            for (int m = 0; m < 4; m++)
                an[m] = *(const bf16x8*)&Ab[((kk + 1) * 4 + quad) * AG + (m * 16 + lx) * 8];
        }
#pragma unroll
        for (int nt = 0; nt < 4; nt++)              // ...current-kk MFMAs
#pragma unroll
            for (int m = 0; m < 4; m++)
                acc[m][nt] = __builtin_amdgcn_mfma_f32_16x16x32_bf16(ac[m], bc[nt], acc[m][nt], 0, 0, 0);
    }
}

// 16x256 @ 256x16 (small layers; weights [slot][256], unpermuted); A rows [mrow0, +16) from K-outer LDS
__device__ __forceinline__ f32x4 gemm16(const bf16* Ab, const bf16* __restrict__ wt,
                                        int mrow0, int lane)
{
    const int quad = lane >> 4, lx = lane & 15;
    f32x4 acc = f32x4{0.f, 0.f, 0.f, 0.f};
#pragma unroll
    for (int kk = 0; kk < 8; kk++) {
        bf16x8 a = *(const bf16x8*)&Ab[(kk * 4 + quad) * AG + (mrow0 + lx) * 8];
        bf16x8 b = *(const bf16x8*)&wt[lx * 256 + kk * 32 + quad * 8];
        acc = __builtin_amdgcn_mfma_f32_16x16x32_bf16(a, b, acc, 0, 0, 0);
    }
    return acc;
}

// bias add in place + per-row partial (sum,sumsq) over this wave's 64 cols via DPP -> redC[nw]
// col(nt,lx) = (nw*2 + (nt>>1))*32 + 2*lx + (nt&1)
__device__ __forceinline__ void ln_partial(f32x4 acc[4][4], const float* __restrict__ bias,
                                           float2 (*redC)[64], int nw, int lane)
{
    const int quad = lane >> 4, lx = lane & 15;
    float s[4][4], ss[4][4];
#pragma unroll
    for (int m = 0; m < 4; m++)
#pragma unroll
        for (int r = 0; r < 4; r++) { s[m][r] = 0.f; ss[m][r] = 0.f; }
#pragma unroll
    for (int sg = 0; sg < 2; sg++) {
        const float2 bv = *(const float2*)&bias[(nw * 2 + sg) * 32 + 2 * lx];
#pragma unroll
        for (int m = 0; m < 4; m++)
#pragma unroll
            for (int r = 0; r < 4; r++) {
                float a0 = acc[m][2 * sg][r] + bv.x;
                float a1 = acc[m][2 * sg + 1][r] + bv.y;
                acc[m][2 * sg][r] = a0; acc[m][2 * sg + 1][r] = a1;
                s[m][r]  += a0 + a1;
                ss[m][r] += a0 * a0 + a1 * a1;
            }
    }
#pragma unroll
    for (int m = 0; m < 4; m++)
#pragma unroll
        for (int r = 0; r < 4; r++) {
            float sv  = dppsum16(s[m][r]);
            float ssv = dppsum16(ss[m][r]);
            if (lx == 0)
                redC[nw][m * 16 + quad * 4 + r] = make_float2(sv, ssv);
        }
}

// normalize + relu in place; stat = redC[0][row] (mean, rstd)
__device__ __forceinline__ void ln_norm(f32x4 acc[4][4],
                                        const float* __restrict__ g, const float* __restrict__ bb,
                                        const float2 (*redC)[64], int nw, int lane)
{
    const int quad = lane >> 4, lx = lane & 15;
    float2 gv[2], bv[2];
#pragma unroll
    for (int sg = 0; sg < 2; sg++) {
        gv[sg] = *(const float2*)&g[(nw * 2 + sg) * 32 + 2 * lx];
        bv[sg] = *(const float2*)&bb[(nw * 2 + sg) * 32 + 2 * lx];
    }
#pragma unroll
    for (int m = 0; m < 4; m++)
#pragma unroll
        for (int r = 0; r < 4; r++) {
            float2 st = redC[0][m * 16 + quad * 4 + r];
#pragma unroll
            for (int sg = 0; sg < 2; sg++) {
                acc[m][2 * sg][r]     = fmaxf((acc[m][2 * sg][r]     - st.x) * st.y * gv[sg].x + bv[sg].x, 0.f);
                acc[m][2 * sg + 1][r] = fmaxf((acc[m][2 * sg + 1][r] - st.x) * st.y * gv[sg].y + bv[sg].y, 0.f);
            }
        }
}

__device__ __forceinline__ void bias_relu(f32x4 acc[4][4], const float* __restrict__ bias,
                                          int nw, int lane)
{
    const int lx = lane & 15;
#pragma unroll
    for (int sg = 0; sg < 2; sg++) {
        const float2 bv = *(const float2*)&bias[(nw * 2 + sg) * 32 + 2 * lx];
#pragma unroll
        for (int m = 0; m < 4; m++)
#pragma unroll
            for (int r = 0; r < 4; r++) {
                acc[m][2 * sg][r]     = fmaxf(acc[m][2 * sg][r]     + bv.x, 0.f);
                acc[m][2 * sg + 1][r] = fmaxf(acc[m][2 * sg + 1][r] + bv.y, 0.f);
            }
    }
}

// shuffle-free store into K-outer A-buf: lane lx owns logical col pair (c, c+1),
// c = (nw*2+sg)*32 + 2lx -> u32 at elem (c>>3)*AG + row*8 + (c&7)
__device__ __forceinline__ void store_A(bf16* Ab, int nw, int lane, const f32x4 acc[4][4])
{
    const int quad = lane >> 4, lx = lane & 15;
#pragma unroll
    for (int m = 0; m < 4; m++)
#pragma unroll
        for (int sg = 0; sg < 2; sg++) {
            const int cg = (nw * 2 + sg) * 4 + (lx >> 2);    // (c>>3)
            const int c7 = (2 * lx) & 7;                     // (c&7)
#pragma unroll
            for (int r = 0; r < 4; r++) {
                int row = m * 16 + quad * 4 + r;
                *(unsigned int*)&Ab[cg * AG + row * 8 + c7] =
                    pack2(acc[m][2 * sg][r], acc[m][2 * sg + 1][r]);
            }
        }
}

// ---------------- main fused head kernel ----------------
// Block = 256 thr = 4 waves; block tile = 64 rows x 256 cols; wave = 64 rows x 64 cols (acc[4][4]).
// Chain-split (z: 0=cls, 1=reg). Barriers: cls 7, reg 5. LDS ~35.8 KB -> 4 blocks/CU;
// (256,3): ~170-reg total cap, 3 waves/SIMD (R9-proven envelope).
__global__ __launch_bounds__(256, 3) void head_kernel(
    const float* __restrict__ hs, const float* __restrict__ init_ref,
    const float* __restrict__ inter_ref,
    const bf16* __restrict__ cw1t, const bf16* __restrict__ cw2t,
    const bf16* __restrict__ rw1t, const bf16* __restrict__ rw2t,
    const bf16* __restrict__ cw3t, const bf16* __restrict__ rw3t,
    const float* __restrict__ cb1, const float* __restrict__ g1, const float* __restrict__ b1,
    const float* __restrict__ cb2, const float* __restrict__ g2, const float* __restrict__ b2,
    const float* __restrict__ cb3,
    const float* __restrict__ rb1, const float* __restrict__ rb2, const float* __restrict__ rb3,
    float* __restrict__ out)
{
    __shared__ __align__(16) bf16 Ab[32 * AG];   // 33792 B
    __shared__ float2 redC[4][64];               // [nw][row]; redC[0] doubles as stat

    const int l     = blockIdx.y;
    const int chain = blockIdx.z;                // 0 = cls, 1 = reg
    const int tid   = threadIdx.x;
    const int wave  = tid >> 6;
    const int lane  = tid & 63;
    const int quad  = lane >> 4;
    const int lx    = lane & 15;
    const int nw    = wave;                      // cols [nw*64, +64)
    const int row0  = blockIdx.x * 64;

    // ---- stage h: wave stages rows [wave*16, +16) into K-outer A-buf ----
#pragma unroll 4
    for (int ri = 0; ri < 16; ri++) {
        const int r = row0 + wave * 16 + ri;
        const int b = r / 900;
        const int q = r - b * 900;
        const float4* src = (const float4*)(hs + (((size_t)l * 900 + q) * 32 + b) * 256);
        float4 vv = src[lane];
        union { bf16 h[4]; uint2 u; } pk;
        pk.h[0] = (bf16)vv.x; pk.h[1] = (bf16)vv.y; pk.h[2] = (bf16)vv.z; pk.h[3] = (bf16)vv.w;
        // k = lane*4: elem = (lane>>1)*AG + row*8 + (lane&1)*4
        *(uint2*)&Ab[(lane >> 1) * AG + (wave * 16 + ri) * 8 + (lane & 1) * 4] = pk.u;
    }
    __syncthreads();                                                    // S0: h staged

    const bf16* w1 = (chain ? rw1t : cw1t) + (size_t)l * 65536;
    const bf16* w2 = (chain ? rw2t : cw2t) + (size_t)l * 65536;
    const bf16* w3 = (chain ? rw3t : cw3t) + (size_t)l * 4096;

    f32x4 acc[4][4];

    // ===== layer 1 =====
    gemm64(Ab, w1, nw, lane, acc);
    if (chain == 0) {
        ln_partial(acc, cb1 + l * 256, redC, nw, lane);
        __syncthreads();                                                // B1: redC ready + A reads done
        if (tid < 64) {
            float sx = 0.f, sy = 0.f;
#pragma unroll
            for (int w = 0; w < 4; w++) { float2 t = redC[w][tid]; sx += t.x; sy += t.y; }
            float mean = sx * (1.f / 256.f);
            float var  = sy * (1.f / 256.f) - mean * mean;
            redC[0][tid] = make_float2(mean, rsqrtf(var + 1e-5f));
        }
        __syncthreads();                                                // B2: stat ready
        ln_norm(acc, g1 + l * 256, b1 + l * 256, redC, nw, lane);
        store_A(Ab, nw, lane, acc);
        __syncthreads();                                                // B3: x1 published
    } else {
        bias_relu(acc, rb1 + l * 256, nw, lane);
        __syncthreads();                                                // A reads done
        store_A(Ab, nw, lane, acc);
        __syncthreads();                                                // y1 published
    }

    // ===== layer 2 =====
    gemm64(Ab, w2, nw, lane, acc);
    if (chain == 0) {
        ln_partial(acc, cb2 + l * 256, redC, nw, lane);
        __syncthreads();                                                // B4
        if (tid < 64) {
            float sx = 0.f, sy = 0.f;
#pragma unroll
            for (int w = 0; w < 4; w++) { float2 t = redC[w][tid]; sx += t.x; sy += t.y; }
            float mean = sx * (1.f / 256.f);
            float var  = sy * (1.f / 256.f) - mean * mean;
            redC[0][tid] = make_float2(mean, rsqrtf(var + 1e-5f));
        }
        __syncthreads();                                                // B5
        ln_norm(acc, g2 + l * 256, b2 + l * 256, redC, nw, lane);
        store_A(Ab, nw, lane, acc);
        __syncthreads();                                                // B6: x2 published
    } else {
        bias_relu(acc, rb2 + l * 256, nw, lane);
        __syncthreads();
        store_A(Ab, nw, lane, acc);
        __syncthreads();                                                // y2 published
    }

    // ===== layer 3: wave handles rows [wave*16, +16) =====
    f32x4 t = gemm16(Ab, w3, wave * 16, lane);
    if (chain == 0) {
        if (lx < 10) {
            const float bv = cb3[l * 10 + lx];
#pragma unroll
            for (int r = 0; r < 4; r++) {
                int row = row0 + wave * 16 + quad * 4 + r;
                out[((size_t)l * 28800 + row) * 10 + lx] = t[r] + bv;
            }
        }
    } else {
        if (lx < 10) {
            const float bv = rb3[l * 10 + lx];
            const float* refp = (l == 0) ? init_ref : (inter_ref + (size_t)(l - 1) * 28800 * 3);
#pragma unroll
            for (int r = 0; r < 4; r++) {
                int row = row0 + wave * 16 + quad * 4 + r;
                float vv = t[r] + bv;
                float o;
                if (lx == 0 || lx == 1 || lx == 4) {
                    int rc = (lx == 4) ? 2 : lx;
                    float x = refp[(size_t)row * 3 + rc];
                    x = fminf(fmaxf(x, 0.f), 1.f);
                    float x1 = fmaxf(x, 1e-5f);
                    float x2 = fmaxf(1.f - x, 1e-5f);
                    float ris = logf(x1) - logf(x2);
                    float sg = 1.f / (1.f + expf(-(vv + ris)));
                    o = (lx == 4) ? (sg * 8.f - 5.f) : (sg * 102.4f - 51.2f);
                } else {
                    o = vv;
                }
                out[(size_t)(6 + l) * 28800 * 10 + (size_t)row * 10 + lx] = o;
            }
        }
    }
}

extern "C" void kernel_launch(void* const* d_in, const int* in_sizes, int n_in,
                              void* d_out, int out_size, void* d_ws, size_t ws_size,
                              hipStream_t stream)
{
    const float* hs        = (const float*)d_in[0];
    const float* init_ref  = (const float*)d_in[1];
    const float* inter_ref = (const float*)d_in[2];
    const float* cls_w1    = (const float*)d_in[3];
    const float* cls_b1    = (const float*)d_in[4];
    const float* ln1_g     = (const float*)d_in[5];
    const float* ln1_b     = (const float*)d_in[6];
    const float* cls_w2    = (const float*)d_in[7];
    const float* cls_b2    = (const float*)d_in[8];
    const float* ln2_g     = (const float*)d_in[9];
    const float* ln2_b     = (const float*)d_in[10];
    const float* cls_w3    = (const float*)d_in[11];
    const float* cls_b3    = (const float*)d_in[12];
    const float* reg_w1    = (const float*)d_in[13];
    const float* reg_b1    = (const float*)d_in[14];
    const float* reg_w2    = (const float*)d_in[15];
    const float* reg_b2    = (const float*)d_in[16];
    const float* reg_w3    = (const float*)d_in[17];
    const float* reg_b3    = (const float*)d_in[18];

    bf16* ws   = (bf16*)d_ws;
    bf16* cw1t = ws;                  // 4 contiguous 6*65536 regions (K-outer packed)
    bf16* cw2t = cw1t + 393216;
    bf16* rw1t = cw2t + 393216;
    bf16* rw2t = rw1t + 393216;
    bf16* cw3t = rw2t + 393216;       // 6*16*256
    bf16* rw3t = cw3t + 24576;

    transpose_all<<<dim3(4, 4, 24), 256, 0, stream>>>(cls_w1, cls_w2, reg_w1, reg_w2, cw1t);
    prep_small<<<192, 256, 0, stream>>>(cls_w3, reg_w3, cw3t, rw3t);

    head_kernel<<<dim3(450, 6, 2), 256, 0, stream>>>(
        hs, init_ref, inter_ref,
        cw1t, cw2t, rw1t, rw2t, cw3t, rw3t,
        cls_b1, ln1_g, ln1_b, cls_b2, ln2_g, ln2_b, cls_b3,
        reg_b1, reg_b2, reg_b3, (float*)d_out);
}

// Round 11
// 421.103 us; speedup vs baseline: 1.2914x; 1.0246x over previous
//
#include <hip/hip_runtime.h>
#include <hip/hip_bf16.h>

typedef __bf16 bf16;
typedef __bf16 bf16x8 __attribute__((ext_vector_type(8)));
typedef float f32x4 __attribute__((ext_vector_type(4)));

// A-buffer: K-outer packed, 64 rows. elem(k,row) = (k>>3)*AG + row*8 + (k&7)
// 32 groups x 528 x 2B = 33792 B. Pad 16 elems/group spreads gemm A-read banks.
#define AG 528

// ---------------- prep: transpose big weights -> bf16, PERMUTED slots, K-OUTER packed ----------------
// Logical col c -> slot ns = (c&~31) | (c odd ? 16+(c&31)/2 : (c&31)/2)   (permute within 32-groups)
// Storage: wpk[k>>3][slot][k&7]  (elem = (k>>3)*2048 + slot*8 + (k&7))
__global__ void transpose_all(const float* __restrict__ w0, const float* __restrict__ w1,
                              const float* __restrict__ w2, const float* __restrict__ w3,
                              bf16* __restrict__ out)
{
    __shared__ float tile[64][65];
    const int mz  = blockIdx.z;             // 0..23 = mat*6 + level
    const int mat = mz / 6;
    const float* srcs[4] = {w0, w1, w2, w3};
    const float* src = srcs[mat] + (size_t)(mz % 6) * 65536;
    bf16* dst = out + (size_t)mz * 65536;
    const int k0 = blockIdx.x * 64;
    const int n0 = blockIdx.y * 64;
    const int tx = threadIdx.x & 63, ty = threadIdx.x >> 6;
#pragma unroll
    for (int i = ty; i < 64; i += 4)
        tile[i][tx] = src[(size_t)(k0 + i) * 256 + n0 + tx];
    __syncthreads();
#pragma unroll
    for (int i = ty; i < 64; i += 4) {
        int n  = n0 + i;
        int o  = n & 31;
        int ns = (n & ~31) | ((o & 1) ? 16 + (o >> 1) : (o >> 1));
        int k  = k0 + tx;
        dst[(size_t)(k >> 3) * 2048 + ns * 8 + (k & 7)] = (bf16)tile[tx][i];
    }
}

// ---------------- prep: [6][256][10] -> [6][16][256] bf16, transposed + zero-padded (both w3s) ----------------
__global__ void prep_small(const float* __restrict__ cw3, const float* __restrict__ rw3,
                           bf16* __restrict__ outc, bf16* __restrict__ outr)
{
    int idx = blockIdx.x * 256 + threadIdx.x;  // 0..49151
    const float* w = (idx < 24576) ? cw3 : rw3;
    bf16* o = (idx < 24576) ? outc : outr;
    int j = (idx < 24576) ? idx : idx - 24576;
    int k = j & 255;
    int n = (j >> 8) & 15;
    int l = j >> 12;
    float v = (n < 10) ? w[((size_t)l * 256 + k) * 10 + n] : 0.0f;
    o[j] = (bf16)v;
}

// ---------------- helpers ----------------
__device__ __forceinline__ unsigned int pack2(float lo, float hi)
{
    union { bf16 h[2]; unsigned int u; } p;
    p.h[0] = (bf16)lo; p.h[1] = (bf16)hi;
    return p.u;
}

template<int CTRL>
__device__ __forceinline__ float dppadd(float x)
{
    int y = __builtin_amdgcn_update_dpp(0, __float_as_int(x), CTRL, 0xF, 0xF, true);
    return x + __int_as_float(y);
}
// full sum across the 16-lane DPP row (= one quad); result broadcast to all 16 lanes
__device__ __forceinline__ float dppsum16(float x)
{
    x = dppadd<0xB1>(x);   // quad_perm [1,0,3,2]
    x = dppadd<0x4E>(x);   // quad_perm [2,3,0,1]
    x = dppadd<0x141>(x);  // row_half_mirror
    x = dppadd<0x140>(x);  // row_mirror
    return x;
}

// 64x64 wave-tile GEMM: ALL 64 rows x cols (slots) [nw*64, +64). acc[4 m][4 nt] = 64 regs (AGPR).
// B prefetched DEPTH 2 (3 rotating chunk buffers, statically indexed under full unroll):
// kk+2's loads are in flight while kk computes -> ~2x16 MFMA (~460 cyc) of cover per load,
// hiding the ~250-cyc L2 latency that the depth-1 version exposed every kk.
__device__ __forceinline__ void gemm64(const bf16* Ab, const bf16* __restrict__ wt,
                                       int nw, int lane, f32x4 acc[4][4])
{
    const int quad = lane >> 4, lx = lane & 15;
#pragma unroll
    for (int m = 0; m < 4; m++)
#pragma unroll
        for (int nt = 0; nt < 4; nt++)
            acc[m][nt] = f32x4{0.f, 0.f, 0.f, 0.f};
    const bf16* base = wt + (size_t)quad * 2048 + (nw * 64 + lx) * 8;
    bf16x8 b[3][4];                      // rotating B chunks (kk, kk+1, kk+2)
    bf16x8 a[2][4];                      // A double buffer
#pragma unroll
    for (int nt = 0; nt < 4; nt++)
        b[0][nt] = *(const bf16x8*)(base + nt * 128);
#pragma unroll
    for (int nt = 0; nt < 4; nt++)
        b[1][nt] = *(const bf16x8*)(base + 8192 + nt * 128);
#pragma unroll
    for (int m = 0; m < 4; m++)
        a[0][m] = *(const bf16x8*)&Ab[quad * AG + (m * 16 + lx) * 8];
#pragma unroll
    for (int kk = 0; kk < 8; kk++) {
        const int cb = kk % 3;           // compile-time under unroll
        const int nb = (kk + 2) % 3;
        const int ca = kk & 1, na = ca ^ 1;
        if (kk < 6) {
            const bf16* bp = base + (kk + 2) * 8192;
#pragma unroll
            for (int nt = 0; nt < 4; nt++)       // kk+2 B loads lead by two steps
                b[nb][nt] = *(const bf16x8*)(bp + nt * 128);
        }
        if (kk < 7) {
#pragma unroll
            for (int m = 0; m < 4; m++)          // kk+1 A loads lead by one step
                a[na][m] = *(const bf16x8*)&Ab[((kk + 1) * 4 + quad) * AG + (m * 16 + lx) * 8];
        }
#pragma unroll
        for (int nt = 0; nt < 4; nt++)
#pragma unroll
            for (int m = 0; m < 4; m++)
                acc[m][nt] = __builtin_amdgcn_mfma_f32_16x16x32_bf16(a[ca][m], b[cb][nt], acc[m][nt], 0, 0, 0);
    }
}

// 16x256 @ 256x16 (small layers; weights [slot][256], unpermuted); A rows [mrow0, +16) from K-outer LDS
__device__ __forceinline__ f32x4 gemm16(const bf16* Ab, const bf16* __restrict__ wt,
                                        int mrow0, int lane)
{
    const int quad = lane >> 4, lx = lane & 15;
    f32x4 acc = f32x4{0.f, 0.f, 0.f, 0.f};
#pragma unroll
    for (int kk = 0; kk < 8; kk++) {
        bf16x8 a = *(const bf16x8*)&Ab[(kk * 4 + quad) * AG + (mrow0 + lx) * 8];
        bf16x8 b = *(const bf16x8*)&wt[lx * 256 + kk * 32 + quad * 8];
        acc = __builtin_amdgcn_mfma_f32_16x16x32_bf16(a, b, acc, 0, 0, 0);
    }
    return acc;
}

// bias add in place + per-row partial (sum,sumsq) over this wave's 64 cols via DPP -> redC[nw]
// col(nt,lx) = (nw*2 + (nt>>1))*32 + 2*lx + (nt&1)
__device__ __forceinline__ void ln_partial(f32x4 acc[4][4], const float* __restrict__ bias,
                                           float2 (*redC)[64], int nw, int lane)
{
    const int quad = lane >> 4, lx = lane & 15;
    float s[4][4], ss[4][4];
#pragma unroll
    for (int m = 0; m < 4; m++)
#pragma unroll
        for (int r = 0; r < 4; r++) { s[m][r] = 0.f; ss[m][r] = 0.f; }
#pragma unroll
    for (int sg = 0; sg < 2; sg++) {
        const float2 bv = *(const float2*)&bias[(nw * 2 + sg) * 32 + 2 * lx];
#pragma unroll
        for (int m = 0; m < 4; m++)
#pragma unroll
            for (int r = 0; r < 4; r++) {
                float a0 = acc[m][2 * sg][r] + bv.x;
                float a1 = acc[m][2 * sg + 1][r] + bv.y;
                acc[m][2 * sg][r] = a0; acc[m][2 * sg + 1][r] = a1;
                s[m][r]  += a0 + a1;
                ss[m][r] += a0 * a0 + a1 * a1;
            }
    }
#pragma unroll
    for (int m = 0; m < 4; m++)
#pragma unroll
        for (int r = 0; r < 4; r++) {
            float sv  = dppsum16(s[m][r]);
            float ssv = dppsum16(ss[m][r]);
            if (lx == 0)
                redC[nw][m * 16 + quad * 4 + r] = make_float2(sv, ssv);
        }
}

// normalize + relu in place; stat = redC[0][row] (mean, rstd)
__device__ __forceinline__ void ln_norm(f32x4 acc[4][4],
                                        const float* __restrict__ g, const float* __restrict__ bb,
                                        const float2 (*redC)[64], int nw, int lane)
{
    const int quad = lane >> 4, lx = lane & 15;
    float2 gv[2], bv[2];
#pragma unroll
    for (int sg = 0; sg < 2; sg++) {
        gv[sg] = *(const float2*)&g[(nw * 2 + sg) * 32 + 2 * lx];
        bv[sg] = *(const float2*)&bb[(nw * 2 + sg) * 32 + 2 * lx];
    }
#pragma unroll
    for (int m = 0; m < 4; m++)
#pragma unroll
        for (int r = 0; r < 4; r++) {
            float2 st = redC[0][m * 16 + quad * 4 + r];
#pragma unroll
            for (int sg = 0; sg < 2; sg++) {
                acc[m][2 * sg][r]     = fmaxf((acc[m][2 * sg][r]     - st.x) * st.y * gv[sg].x + bv[sg].x, 0.f);
                acc[m][2 * sg + 1][r] = fmaxf((acc[m][2 * sg + 1][r] - st.x) * st.y * gv[sg].y + bv[sg].y, 0.f);
            }
        }
}

__device__ __forceinline__ void bias_relu(f32x4 acc[4][4], const float* __restrict__ bias,
                                          int nw, int lane)
{
    const int lx = lane & 15;
#pragma unroll
    for (int sg = 0; sg < 2; sg++) {
        const float2 bv = *(const float2*)&bias[(nw * 2 + sg) * 32 + 2 * lx];
#pragma unroll
        for (int m = 0; m < 4; m++)
#pragma unroll
            for (int r = 0; r < 4; r++) {
                acc[m][2 * sg][r]     = fmaxf(acc[m][2 * sg][r]     + bv.x, 0.f);
                acc[m][2 * sg + 1][r] = fmaxf(acc[m][2 * sg + 1][r] + bv.y, 0.f);
            }
    }
}

// shuffle-free store into K-outer A-buf: lane lx owns logical col pair (c, c+1),
// c = (nw*2+sg)*32 + 2lx -> u32 at elem (c>>3)*AG + row*8 + (c&7)
__device__ __forceinline__ void store_A(bf16* Ab, int nw, int lane, const f32x4 acc[4][4])
{
    const int quad = lane >> 4, lx = lane & 15;
#pragma unroll
    for (int m = 0; m < 4; m++)
#pragma unroll
        for (int sg = 0; sg < 2; sg++) {
            const int cg = (nw * 2 + sg) * 4 + (lx >> 2);    // (c>>3)
            const int c7 = (2 * lx) & 7;                     // (c&7)
#pragma unroll
            for (int r = 0; r < 4; r++) {
                int row = m * 16 + quad * 4 + r;
                *(unsigned int*)&Ab[cg * AG + row * 8 + c7] =
                    pack2(acc[m][2 * sg][r], acc[m][2 * sg + 1][r]);
            }
        }
}

// ---------------- main fused head kernel ----------------
// Block = 256 thr = 4 waves; block tile = 64 rows x 256 cols; wave = 64 rows x 64 cols (acc[4][4]).
// Chain-split (z: 0=cls, 1=reg). Barriers: cls 7, reg 5. (256,3): ~170-reg total cap, 3 waves/SIMD.
__global__ __launch_bounds__(256, 3) void head_kernel(
    const float* __restrict__ hs, const float* __restrict__ init_ref,
    const float* __restrict__ inter_ref,
    const bf16* __restrict__ cw1t, const bf16* __restrict__ cw2t,
    const bf16* __restrict__ rw1t, const bf16* __restrict__ rw2t,
    const bf16* __restrict__ cw3t, const bf16* __restrict__ rw3t,
    const float* __restrict__ cb1, const float* __restrict__ g1, const float* __restrict__ b1,
    const float* __restrict__ cb2, const float* __restrict__ g2, const float* __restrict__ b2,
    const float* __restrict__ cb3,
    const float* __restrict__ rb1, const float* __restrict__ rb2, const float* __restrict__ rb3,
    float* __restrict__ out)
{
    __shared__ __align__(16) bf16 Ab[32 * AG];   // 33792 B
    __shared__ float2 redC[4][64];               // [nw][row]; redC[0] doubles as stat

    const int l     = blockIdx.y;
    const int chain = blockIdx.z;                // 0 = cls, 1 = reg
    const int tid   = threadIdx.x;
    const int wave  = tid >> 6;
    const int lane  = tid & 63;
    const int quad  = lane >> 4;
    const int lx    = lane & 15;
    const int nw    = wave;                      // cols [nw*64, +64)
    const int row0  = blockIdx.x * 64;

    // ---- stage h: wave stages rows [wave*16, +16); 2 rows/iter, b128 writes.
    // Bank check: dword addr = g*264 + row*4 -> per-iter banks {g*8%32}+{0..3} over rows {2i,2i+1}
    // cover ALL 32 banks -> minimum-cycle LDS writes (old uint2 scheme hit only 16 banks). ----
#pragma unroll
    for (int it = 0; it < 8; it++) {
        const int ri = it * 2 + (lane >> 5);                 // 0..15
        const int g  = lane & 31;                            // k-group
        const int r  = row0 + wave * 16 + ri;
        const int b  = r / 900;
        const int q  = r - b * 900;
        const float* src = hs + (((size_t)l * 900 + q) * 32 + b) * 256 + g * 8;
        float4 f0 = *(const float4*)(src);
        float4 f1 = *(const float4*)(src + 4);
        union { unsigned int w[4]; uint4 u; } pk;
        pk.w[0] = pack2(f0.x, f0.y);
        pk.w[1] = pack2(f0.z, f0.w);
        pk.w[2] = pack2(f1.x, f1.y);
        pk.w[3] = pack2(f1.z, f1.w);
        *(uint4*)&Ab[g * AG + (wave * 16 + ri) * 8] = pk.u;
    }
    __syncthreads();                                                    // S0: h staged

    const bf16* w1 = (chain ? rw1t : cw1t) + (size_t)l * 65536;
    const bf16* w2 = (chain ? rw2t : cw2t) + (size_t)l * 65536;
    const bf16* w3 = (chain ? rw3t : cw3t) + (size_t)l * 4096;

    f32x4 acc[4][4];

    // ===== layer 1 =====
    gemm64(Ab, w1, nw, lane, acc);
    if (chain == 0) {
        ln_partial(acc, cb1 + l * 256, redC, nw, lane);
        __syncthreads();                                                // B1: redC ready + A reads done
        if (tid < 64) {
            float sx = 0.f, sy = 0.f;
#pragma unroll
            for (int w = 0; w < 4; w++) { float2 t = redC[w][tid]; sx += t.x; sy += t.y; }
            float mean = sx * (1.f / 256.f);
            float var  = sy * (1.f / 256.f) - mean * mean;
            redC[0][tid] = make_float2(mean, rsqrtf(var + 1e-5f));
        }
        __syncthreads();                                                // B2: stat ready
        ln_norm(acc, g1 + l * 256, b1 + l * 256, redC, nw, lane);
        store_A(Ab, nw, lane, acc);
        __syncthreads();                                                // B3: x1 published
    } else {
        bias_relu(acc, rb1 + l * 256, nw, lane);
        __syncthreads();                                                // A reads done
        store_A(Ab, nw, lane, acc);
        __syncthreads();                                                // y1 published
    }

    // ===== layer 2 =====
    gemm64(Ab, w2, nw, lane, acc);
    if (chain == 0) {
        ln_partial(acc, cb2 + l * 256, redC, nw, lane);
        __syncthreads();                                                // B4
        if (tid < 64) {
            float sx = 0.f, sy = 0.f;
#pragma unroll
            for (int w = 0; w < 4; w++) { float2 t = redC[w][tid]; sx += t.x; sy += t.y; }
            float mean = sx * (1.f / 256.f);
            float var  = sy * (1.f / 256.f) - mean * mean;
            redC[0][tid] = make_float2(mean, rsqrtf(var + 1e-5f));
        }
        __syncthreads();                                                // B5
        ln_norm(acc, g2 + l * 256, b2 + l * 256, redC, nw, lane);
        store_A(Ab, nw, lane, acc);
        __syncthreads();                                                // B6: x2 published
    } else {
        bias_relu(acc, rb2 + l * 256, nw, lane);
        __syncthreads();
        store_A(Ab, nw, lane, acc);
        __syncthreads();                                                // y2 published
    }

    // ===== layer 3: wave handles rows [wave*16, +16) =====
    f32x4 t = gemm16(Ab, w3, wave * 16, lane);
    if (chain == 0) {
        if (lx < 10) {
            const float bv = cb3[l * 10 + lx];
#pragma unroll
            for (int r = 0; r < 4; r++) {
                int row = row0 + wave * 16 + quad * 4 + r;
                out[((size_t)l * 28800 + row) * 10 + lx] = t[r] + bv;
            }
        }
    } else {
        if (lx < 10) {
            const float bv = rb3[l * 10 + lx];
            const float* refp = (l == 0) ? init_ref : (inter_ref + (size_t)(l - 1) * 28800 * 3);
#pragma unroll
            for (int r = 0; r < 4; r++) {
                int row = row0 + wave * 16 + quad * 4 + r;
                float vv = t[r] + bv;
                float o;
                if (lx == 0 || lx == 1 || lx == 4) {
                    int rc = (lx == 4) ? 2 : lx;
                    float x = refp[(size_t)row * 3 + rc];
                    x = fminf(fmaxf(x, 0.f), 1.f);
                    float x1 = fmaxf(x, 1e-5f);
                    float x2 = fmaxf(1.f - x, 1e-5f);
                    float ris = logf(x1) - logf(x2);
                    float sg = 1.f / (1.f + expf(-(vv + ris)));
                    o = (lx == 4) ? (sg * 8.f - 5.f) : (sg * 102.4f - 51.2f);
                } else {
                    o = vv;
                }
                out[(size_t)(6 + l) * 28800 * 10 + (size_t)row * 10 + lx] = o;
            }
        }
    }
}

extern "C" void kernel_launch(void* const* d_in, const int* in_sizes, int n_in,
                              void* d_out, int out_size, void* d_ws, size_t ws_size,
                              hipStream_t stream)
{
    const float* hs        = (const float*)d_in[0];
    const float* init_ref  = (const float*)d_in[1];
    const float* inter_ref = (const float*)d_in[2];
    const float* cls_w1    = (const float*)d_in[3];
    const float* cls_b1    = (const float*)d_in[4];
    const float* ln1_g     = (const float*)d_in[5];
    const float* ln1_b     = (const float*)d_in[6];
    const float* cls_w2    = (const float*)d_in[7];
    const float* cls_b2    = (const float*)d_in[8];
    const float* ln2_g     = (const float*)d_in[9];
    const float* ln2_b     = (const float*)d_in[10];
    const float* cls_w3    = (const float*)d_in[11];
    const float* cls_b3    = (const float*)d_in[12];
    const float* reg_w1    = (const float*)d_in[13];
    const float* reg_b1    = (const float*)d_in[14];
    const float* reg_w2    = (const float*)d_in[15];
    const float* reg_b2    = (const float*)d_in[16];
    const float* reg_w3    = (const float*)d_in[17];
    const float* reg_b3    = (const float*)d_in[18];

    bf16* ws   = (bf16*)d_ws;
    bf16* cw1t = ws;                  // 4 contiguous 6*65536 regions (K-outer packed)
    bf16* cw2t = cw1t + 393216;
    bf16* rw1t = cw2t + 393216;
    bf16* rw2t = rw1t + 393216;
    bf16* cw3t = rw2t + 393216;       // 6*16*256
    bf16* rw3t = cw3t + 24576;

    transpose_all<<<dim3(4, 4, 24), 256, 0, stream>>>(cls_w1, cls_w2, reg_w1, reg_w2, cw1t);
    prep_small<<<192, 256, 0, stream>>>(cls_w3, reg_w3, cw3t, rw3t);

    head_kernel<<<dim3(450, 6, 2), 256, 0, stream>>>(
        hs, init_ref, inter_ref,
        cw1t, cw2t, rw1t, rw2t, cw3t, rw3t,
        cls_b1, ln1_g, ln1_b, cls_b2, ln2_g, ln2_b, cls_b3,
        reg_b1, reg_b2, reg_b3, (float*)d_out);
}

// Round 12
// 384.955 us; speedup vs baseline: 1.4126x; 1.0939x over previous
//
#include <hip/hip_runtime.h>
#include <hip/hip_bf16.h>

typedef __bf16 bf16;
typedef __bf16 bf16x8 __attribute__((ext_vector_type(8)));
typedef float f32x4 __attribute__((ext_vector_type(4)));

// A-buffer: K-outer packed, 64 rows. elem(k,row) = (k>>3)*AG + row*8 + (k&7)
// 32 groups x 528 x 2B = 33792 B. Pad 16 elems/group spreads gemm A-read banks.
#define AG 528

// ---------------- prep (single launch): transpose big weights + pack small weights ----------------
// Big: logical col c -> slot ns = (c&~31) | (c odd ? 16+(c&31)/2 : (c&31)/2); K-outer
//      wpk[k>>3][slot][k&7] (elem = (k>>3)*2048 + slot*8 + (k&7)).
// Small: [6][256][10] -> [6][16][256] transposed + zero-padded.
__global__ void prep_all(const float* __restrict__ w0, const float* __restrict__ w1,
                         const float* __restrict__ w2, const float* __restrict__ w3,
                         const float* __restrict__ cw3, const float* __restrict__ rw3,
                         bf16* __restrict__ out, bf16* __restrict__ outc, bf16* __restrict__ outr)
{
    if (blockIdx.z < 24) {
        __shared__ float tile[64][65];
        const int mz  = blockIdx.z;             // 0..23 = mat*6 + level
        const int mat = mz / 6;
        const float* srcs[4] = {w0, w1, w2, w3};
        const float* src = srcs[mat] + (size_t)(mz % 6) * 65536;
        bf16* dst = out + (size_t)mz * 65536;
        const int k0 = blockIdx.x * 64;
        const int n0 = blockIdx.y * 64;
        const int tx = threadIdx.x & 63, ty = threadIdx.x >> 6;
#pragma unroll
        for (int i = ty; i < 64; i += 4)
            tile[i][tx] = src[(size_t)(k0 + i) * 256 + n0 + tx];
        __syncthreads();
#pragma unroll
        for (int i = ty; i < 64; i += 4) {
            int n  = n0 + i;
            int o  = n & 31;
            int ns = (n & ~31) | ((o & 1) ? 16 + (o >> 1) : (o >> 1));
            int k  = k0 + tx;
            dst[(size_t)(k >> 3) * 2048 + ns * 8 + (k & 7)] = (bf16)tile[tx][i];
        }
    } else {
        // small weights: 32 blocks (z=24,25 x 4x4), 6 elems/thread
        const int bid = (blockIdx.z - 24) * 16 + blockIdx.y * 4 + blockIdx.x;  // 0..31
#pragma unroll
        for (int t = 0; t < 6; t++) {
            int idx = (bid * 6 + t) * 256 + threadIdx.x;   // 0..49151
            const float* w = (idx < 24576) ? cw3 : rw3;
            bf16* o = (idx < 24576) ? outc : outr;
            int j = (idx < 24576) ? idx : idx - 24576;
            int k = j & 255;
            int n = (j >> 8) & 15;
            int l = j >> 12;
            float v = (n < 10) ? w[((size_t)l * 256 + k) * 10 + n] : 0.0f;
            o[j] = (bf16)v;
        }
    }
}

// ---------------- helpers ----------------
__device__ __forceinline__ unsigned int pack2(float lo, float hi)
{
    union { bf16 h[2]; unsigned int u; } p;
    p.h[0] = (bf16)lo; p.h[1] = (bf16)hi;
    return p.u;
}

template<int CTRL>
__device__ __forceinline__ float dppadd(float x)
{
    int y = __builtin_amdgcn_update_dpp(0, __float_as_int(x), CTRL, 0xF, 0xF, true);
    return x + __int_as_float(y);
}
// full sum across the 16-lane DPP row (= one quad); result broadcast to all 16 lanes
__device__ __forceinline__ float dppsum16(float x)
{
    x = dppadd<0xB1>(x);   // quad_perm [1,0,3,2]
    x = dppadd<0x4E>(x);   // quad_perm [2,3,0,1]
    x = dppadd<0x141>(x);  // row_half_mirror
    x = dppadd<0x140>(x);  // row_mirror
    return x;
}

// 64x64 wave-tile GEMM: ALL 64 rows x cols (slots) [nw*64, +64). acc[4 m][4 nt] = 64 regs (AGPR).
// B prefetched depth 2 (rotating chunks); s_setprio(1) wraps the MFMA cluster (T5): cls/reg blocks
// co-resident at different phases -> scheduler favors MFMA-issuing waves over epilogue-VALU waves.
__device__ __forceinline__ void gemm64(const bf16* Ab, const bf16* __restrict__ wt,
                                       int nw, int lane, f32x4 acc[4][4])
{
    const int quad = lane >> 4, lx = lane & 15;
#pragma unroll
    for (int m = 0; m < 4; m++)
#pragma unroll
        for (int nt = 0; nt < 4; nt++)
            acc[m][nt] = f32x4{0.f, 0.f, 0.f, 0.f};
    const bf16* base = wt + (size_t)quad * 2048 + (nw * 64 + lx) * 8;
    bf16x8 b[3][4];                      // rotating B chunks (kk, kk+1, kk+2)
    bf16x8 a[2][4];                      // A double buffer
#pragma unroll
    for (int nt = 0; nt < 4; nt++)
        b[0][nt] = *(const bf16x8*)(base + nt * 128);
#pragma unroll
    for (int nt = 0; nt < 4; nt++)
        b[1][nt] = *(const bf16x8*)(base + 8192 + nt * 128);
#pragma unroll
    for (int m = 0; m < 4; m++)
        a[0][m] = *(const bf16x8*)&Ab[quad * AG + (m * 16 + lx) * 8];
#pragma unroll
    for (int kk = 0; kk < 8; kk++) {
        const int cb = kk % 3;           // compile-time under unroll
        const int nb = (kk + 2) % 3;
        const int ca = kk & 1, na = ca ^ 1;
        if (kk < 6) {
            const bf16* bp = base + (kk + 2) * 8192;
#pragma unroll
            for (int nt = 0; nt < 4; nt++)       // kk+2 B loads lead by two steps
                b[nb][nt] = *(const bf16x8*)(bp + nt * 128);
        }
        if (kk < 7) {
#pragma unroll
            for (int m = 0; m < 4; m++)          // kk+1 A loads lead by one step
                a[na][m] = *(const bf16x8*)&Ab[((kk + 1) * 4 + quad) * AG + (m * 16 + lx) * 8];
        }
        __builtin_amdgcn_s_setprio(1);
#pragma unroll
        for (int nt = 0; nt < 4; nt++)
#pragma unroll
            for (int m = 0; m < 4; m++)
                acc[m][nt] = __builtin_amdgcn_mfma_f32_16x16x32_bf16(a[ca][m], b[cb][nt], acc[m][nt], 0, 0, 0);
        __builtin_amdgcn_s_setprio(0);
    }
}

// 16x256 @ 256x16 (small layers; weights [slot][256], unpermuted); A rows [mrow0, +16) from K-outer LDS
__device__ __forceinline__ f32x4 gemm16(const bf16* Ab, const bf16* __restrict__ wt,
                                        int mrow0, int lane)
{
    const int quad = lane >> 4, lx = lane & 15;
    f32x4 acc = f32x4{0.f, 0.f, 0.f, 0.f};
#pragma unroll
    for (int kk = 0; kk < 8; kk++) {
        bf16x8 a = *(const bf16x8*)&Ab[(kk * 4 + quad) * AG + (mrow0 + lx) * 8];
        bf16x8 b = *(const bf16x8*)&wt[lx * 256 + kk * 32 + quad * 8];
        acc = __builtin_amdgcn_mfma_f32_16x16x32_bf16(a, b, acc, 0, 0, 0);
    }
    return acc;
}

// bias add in place + per-row partial (sum,sumsq) over this wave's 64 cols via DPP -> redC[nw]
// col(nt,lx) = (nw*2 + (nt>>1))*32 + 2*lx + (nt&1)
__device__ __forceinline__ void ln_partial(f32x4 acc[4][4], const float* __restrict__ bias,
                                           float2 (*redC)[64], int nw, int lane)
{
    const int quad = lane >> 4, lx = lane & 15;
    float s[4][4], ss[4][4];
#pragma unroll
    for (int m = 0; m < 4; m++)
#pragma unroll
        for (int r = 0; r < 4; r++) { s[m][r] = 0.f; ss[m][r] = 0.f; }
#pragma unroll
    for (int sg = 0; sg < 2; sg++) {
        const float2 bv = *(const float2*)&bias[(nw * 2 + sg) * 32 + 2 * lx];
#pragma unroll
        for (int m = 0; m < 4; m++)
#pragma unroll
            for (int r = 0; r < 4; r++) {
                float a0 = acc[m][2 * sg][r] + bv.x;
                float a1 = acc[m][2 * sg + 1][r] + bv.y;
                acc[m][2 * sg][r] = a0; acc[m][2 * sg + 1][r] = a1;
                s[m][r]  += a0 + a1;
                ss[m][r] += a0 * a0 + a1 * a1;
            }
    }
#pragma unroll
    for (int m = 0; m < 4; m++)
#pragma unroll
        for (int r = 0; r < 4; r++) {
            float sv  = dppsum16(s[m][r]);
            float ssv = dppsum16(ss[m][r]);
            if (lx == 0)
                redC[nw][m * 16 + quad * 4 + r] = make_float2(sv, ssv);
        }
}

// normalize + relu in place. Stats computed REDUNDANTLY per wave from the 4 partials
// (LDS broadcast reads: all 16 lanes of a quad hit the same address -> conflict-free).
// Replaces the serialized tid<64 reduce + one barrier.
__device__ __forceinline__ void ln_norm2(f32x4 acc[4][4],
                                         const float* __restrict__ g, const float* __restrict__ bb,
                                         const float2 (*redC)[64], int nw, int lane)
{
    const int quad = lane >> 4, lx = lane & 15;
    float2 gv[2], bv[2];
#pragma unroll
    for (int sg = 0; sg < 2; sg++) {
        gv[sg] = *(const float2*)&g[(nw * 2 + sg) * 32 + 2 * lx];
        bv[sg] = *(const float2*)&bb[(nw * 2 + sg) * 32 + 2 * lx];
    }
#pragma unroll
    for (int m = 0; m < 4; m++)
#pragma unroll
        for (int r = 0; r < 4; r++) {
            const int row = m * 16 + quad * 4 + r;
            float2 p0 = redC[0][row], p1 = redC[1][row], p2 = redC[2][row], p3 = redC[3][row];
            float mean = ((p0.x + p1.x) + (p2.x + p3.x)) * (1.f / 256.f);
            float var  = ((p0.y + p1.y) + (p2.y + p3.y)) * (1.f / 256.f) - mean * mean;
            float rs   = rsqrtf(var + 1e-5f);
#pragma unroll
            for (int sg = 0; sg < 2; sg++) {
                acc[m][2 * sg][r]     = fmaxf((acc[m][2 * sg][r]     - mean) * rs * gv[sg].x + bv[sg].x, 0.f);
                acc[m][2 * sg + 1][r] = fmaxf((acc[m][2 * sg + 1][r] - mean) * rs * gv[sg].y + bv[sg].y, 0.f);
            }
        }
}

__device__ __forceinline__ void bias_relu(f32x4 acc[4][4], const float* __restrict__ bias,
                                          int nw, int lane)
{
    const int lx = lane & 15;
#pragma unroll
    for (int sg = 0; sg < 2; sg++) {
        const float2 bv = *(const float2*)&bias[(nw * 2 + sg) * 32 + 2 * lx];
#pragma unroll
        for (int m = 0; m < 4; m++)
#pragma unroll
            for (int r = 0; r < 4; r++) {
                acc[m][2 * sg][r]     = fmaxf(acc[m][2 * sg][r]     + bv.x, 0.f);
                acc[m][2 * sg + 1][r] = fmaxf(acc[m][2 * sg + 1][r] + bv.y, 0.f);
            }
    }
}

// shuffle-free store into K-outer A-buf: lane lx owns logical col pair (c, c+1),
// c = (nw*2+sg)*32 + 2lx -> u32 at elem (c>>3)*AG + row*8 + (c&7)
__device__ __forceinline__ void store_A(bf16* Ab, int nw, int lane, const f32x4 acc[4][4])
{
    const int quad = lane >> 4, lx = lane & 15;
#pragma unroll
    for (int m = 0; m < 4; m++)
#pragma unroll
        for (int sg = 0; sg < 2; sg++) {
            const int cg = (nw * 2 + sg) * 4 + (lx >> 2);    // (c>>3)
            const int c7 = (2 * lx) & 7;                     // (c&7)
#pragma unroll
            for (int r = 0; r < 4; r++) {
                int row = m * 16 + quad * 4 + r;
                *(unsigned int*)&Ab[cg * AG + row * 8 + c7] =
                    pack2(acc[m][2 * sg][r], acc[m][2 * sg + 1][r]);
            }
        }
}

// ---------------- main fused head kernel ----------------
// Block = 256 thr = 4 waves; block tile = 64 rows x 256 cols; wave = 64 rows x 64 cols (acc[4][4]).
// Chain-split (z: 0=cls, 1=reg). Barriers: cls 5 (was 7), reg 5. (256,3): ~170-reg cap, 3 waves/SIMD.
__global__ __launch_bounds__(256, 3) void head_kernel(
    const float* __restrict__ hs, const float* __restrict__ init_ref,
    const float* __restrict__ inter_ref,
    const bf16* __restrict__ cw1t, const bf16* __restrict__ cw2t,
    const bf16* __restrict__ rw1t, const bf16* __restrict__ rw2t,
    const bf16* __restrict__ cw3t, const bf16* __restrict__ rw3t,
    const float* __restrict__ cb1, const float* __restrict__ g1, const float* __restrict__ b1,
    const float* __restrict__ cb2, const float* __restrict__ g2, const float* __restrict__ b2,
    const float* __restrict__ cb3,
    const float* __restrict__ rb1, const float* __restrict__ rb2, const float* __restrict__ rb3,
    float* __restrict__ out)
{
    __shared__ __align__(16) bf16 Ab[32 * AG];   // 33792 B
    __shared__ float2 redC[4][64];               // [nw][row] partials

    const int l     = blockIdx.y;
    const int chain = blockIdx.z;                // 0 = cls, 1 = reg
    const int tid   = threadIdx.x;
    const int wave  = tid >> 6;
    const int lane  = tid & 63;
    const int quad  = lane >> 4;
    const int lx    = lane & 15;
    const int nw    = wave;                      // cols [nw*64, +64)
    const int row0  = blockIdx.x * 64;

    // ---- stage h: wave stages rows [wave*16, +16); 2 rows/iter, b128 writes (full 32-bank cover) ----
#pragma unroll
    for (int it = 0; it < 8; it++) {
        const int ri = it * 2 + (lane >> 5);                 // 0..15
        const int g  = lane & 31;                            // k-group
        const int r  = row0 + wave * 16 + ri;
        const int b  = r / 900;
        const int q  = r - b * 900;
        const float* src = hs + (((size_t)l * 900 + q) * 32 + b) * 256 + g * 8;
        float4 f0 = *(const float4*)(src);
        float4 f1 = *(const float4*)(src + 4);
        union { unsigned int w[4]; uint4 u; } pk;
        pk.w[0] = pack2(f0.x, f0.y);
        pk.w[1] = pack2(f0.z, f0.w);
        pk.w[2] = pack2(f1.x, f1.y);
        pk.w[3] = pack2(f1.z, f1.w);
        *(uint4*)&Ab[g * AG + (wave * 16 + ri) * 8] = pk.u;
    }
    __syncthreads();                                                    // S0: h staged

    const bf16* w1 = (chain ? rw1t : cw1t) + (size_t)l * 65536;
    const bf16* w2 = (chain ? rw2t : cw2t) + (size_t)l * 65536;
    const bf16* w3 = (chain ? rw3t : cw3t) + (size_t)l * 4096;

    f32x4 acc[4][4];

    // ===== layer 1 =====
    gemm64(Ab, w1, nw, lane, acc);
    if (chain == 0) {
        ln_partial(acc, cb1 + l * 256, redC, nw, lane);
        __syncthreads();                                                // B1: partials ready + A reads done
        ln_norm2(acc, g1 + l * 256, b1 + l * 256, redC, nw, lane);
        store_A(Ab, nw, lane, acc);
        __syncthreads();                                                // B2: x1 published
    } else {
        bias_relu(acc, rb1 + l * 256, nw, lane);
        __syncthreads();                                                // A reads done
        store_A(Ab, nw, lane, acc);
        __syncthreads();                                                // y1 published
    }

    // ===== layer 2 =====
    gemm64(Ab, w2, nw, lane, acc);
    if (chain == 0) {
        ln_partial(acc, cb2 + l * 256, redC, nw, lane);
        __syncthreads();                                                // B3
        ln_norm2(acc, g2 + l * 256, b2 + l * 256, redC, nw, lane);
        store_A(Ab, nw, lane, acc);
        __syncthreads();                                                // B4: x2 published
    } else {
        bias_relu(acc, rb2 + l * 256, nw, lane);
        __syncthreads();
        store_A(Ab, nw, lane, acc);
        __syncthreads();                                                // y2 published
    }

    // ===== layer 3: wave handles rows [wave*16, +16) =====
    f32x4 t = gemm16(Ab, w3, wave * 16, lane);
    if (chain == 0) {
        if (lx < 10) {
            const float bv = cb3[l * 10 + lx];
#pragma unroll
            for (int r = 0; r < 4; r++) {
                int row = row0 + wave * 16 + quad * 4 + r;
                out[((size_t)l * 28800 + row) * 10 + lx] = t[r] + bv;
            }
        }
    } else {
        if (lx < 10) {
            const float bv = rb3[l * 10 + lx];
            const float* refp = (l == 0) ? init_ref : (inter_ref + (size_t)(l - 1) * 28800 * 3);
#pragma unroll
            for (int r = 0; r < 4; r++) {
                int row = row0 + wave * 16 + quad * 4 + r;
                float vv = t[r] + bv;
                float o;
                if (lx == 0 || lx == 1 || lx == 4) {
                    int rc = (lx == 4) ? 2 : lx;
                    float x = refp[(size_t)row * 3 + rc];
                    x = fminf(fmaxf(x, 0.f), 1.f);
                    float x1 = fmaxf(x, 1e-5f);
                    float x2 = fmaxf(1.f - x, 1e-5f);
                    float ris = logf(x1) - logf(x2);
                    float sg = 1.f / (1.f + expf(-(vv + ris)));
                    o = (lx == 4) ? (sg * 8.f - 5.f) : (sg * 102.4f - 51.2f);
                } else {
                    o = vv;
                }
                out[(size_t)(6 + l) * 28800 * 10 + (size_t)row * 10 + lx] = o;
            }
        }
    }
}

extern "C" void kernel_launch(void* const* d_in, const int* in_sizes, int n_in,
                              void* d_out, int out_size, void* d_ws, size_t ws_size,
                              hipStream_t stream)
{
    const float* hs        = (const float*)d_in[0];
    const float* init_ref  = (const float*)d_in[1];
    const float* inter_ref = (const float*)d_in[2];
    const float* cls_w1    = (const float*)d_in[3];
    const float* cls_b1    = (const float*)d_in[4];
    const float* ln1_g     = (const float*)d_in[5];
    const float* ln1_b     = (const float*)d_in[6];
    const float* cls_w2    = (const float*)d_in[7];
    const float* cls_b2    = (const float*)d_in[8];
    const float* ln2_g     = (const float*)d_in[9];
    const float* ln2_b     = (const float*)d_in[10];
    const float* cls_w3    = (const float*)d_in[11];
    const float* cls_b3    = (const float*)d_in[12];
    const float* reg_w1    = (const float*)d_in[13];
    const float* reg_b1    = (const float*)d_in[14];
    const float* reg_w2    = (const float*)d_in[15];
    const float* reg_b2    = (const float*)d_in[16];
    const float* reg_w3    = (const float*)d_in[17];
    const float* reg_b3    = (const float*)d_in[18];

    bf16* ws   = (bf16*)d_ws;
    bf16* cw1t = ws;                  // 4 contiguous 6*65536 regions (K-outer packed)
    bf16* cw2t = cw1t + 393216;
    bf16* rw1t = cw2t + 393216;
    bf16* rw2t = rw1t + 393216;
    bf16* cw3t = rw2t + 393216;       // 6*16*256
    bf16* rw3t = cw3t + 24576;

    prep_all<<<dim3(4, 4, 26), 256, 0, stream>>>(cls_w1, cls_w2, reg_w1, reg_w2,
                                                 cls_w3, reg_w3, cw1t, cw3t, rw3t);

    head_kernel<<<dim3(450, 6, 2), 256, 0, stream>>>(
        hs, init_ref, inter_ref,
        cw1t, cw2t, rw1t, rw2t, cw3t, rw3t,
        cls_b1, ln1_g, ln1_b, cls_b2, ln2_g, ln2_b, cls_b3,
        reg_b1, reg_b2, reg_b3, (float*)d_out);
}